// Round 1
// baseline (1628.529 us; speedup 1.0000x reference)
//
#include <hip/hip_runtime.h>

// hexagdly conv2d: B=8, Cin=64, H=W=256, Cout=128, fp32.
// out[b,co,h,w] = bias[co]
//   + sum_ci sum_{t=0..2} x[b,ci,h-1+t,w] * k0[co,ci,t]
//   + (w even) sum_ci sum_{kh,kw} x[b,ci,h-1+kh,w-1+2kw] * k1[co,ci,kh,kw]
//   + (w odd)  sum_ci sum_{kh,kw} x[b,ci,h+kh,  w-1+2kw] * k1[co,ci,kh,kw]
// Zero-padded outside [0,H)x[0,W).

#define CIN   64
#define COUT  128
#define HH    256
#define WW    256
#define TILE  8
#define CICHUNK 8

__global__ __launch_bounds__(256, 2)
void hexconv_fp32(const float* __restrict__ x,
                  const float* __restrict__ k0,
                  const float* __restrict__ k1,
                  const float* __restrict__ bias,
                  float* __restrict__ out)
{
    // input tile: all 64 ci, (8+2)x(8+2) halo, col stride padded to 12
    __shared__ float xs[CIN][TILE + 2][12];          // 30720 B
    // weights for an 8-ci chunk: [ci][tap][co], tap 0..2 = k0, 3..6 = k1
    __shared__ float wl[CICHUNK][7][COUT];           // 28672 B

    const int b   = blockIdx.z;
    const int h0  = blockIdx.y * TILE;
    const int w0  = blockIdx.x * TILE;
    const int tid = threadIdx.x;

    // ---- stage input tile (zero-fill halo out of bounds) ----
    const float* xb = x + (size_t)b * CIN * HH * WW;
    for (int i = tid; i < CIN * 10 * 10; i += 256) {
        int ci = i / 100;
        int rr = (i % 100) / 10;
        int cc = i % 10;
        int gh = h0 - 1 + rr;
        int gw = w0 - 1 + cc;
        float v = 0.0f;
        if ((unsigned)gh < HH && (unsigned)gw < WW)
            v = xb[(ci * HH + gh) * WW + gw];
        xs[ci][rr][cc] = v;
    }

    const int ty  = tid >> 4;        // 0..15 -> co tile
    const int tx  = tid & 15;        // 0..15 -> position group
    const int co0 = ty * 8;
    const int r   = tx >> 1;         // tile row 0..7
    const int c0  = (tx & 1) * 4;    // tile col base {0,4}

    float acc[8][4];
    #pragma unroll
    for (int j = 0; j < 8; ++j)
        #pragma unroll
        for (int k = 0; k < 4; ++k) acc[j][k] = 0.0f;

    __syncthreads();

    for (int cib = 0; cib < CIN; cib += CICHUNK) {
        // ---- stage weight chunk: wl[ci8][tap][co] ----
        // k0 part (taps 0..2): consecutive tids read consecutive (ci,kh) of one co
        for (int i = tid; i < CICHUNK * 3 * COUT; i += 256) {
            int co  = i / (CICHUNK * 3);
            int rr  = i % (CICHUNK * 3);
            int ci8 = rr / 3;
            int kh  = rr % 3;
            wl[ci8][kh][co] = k0[(co * CIN + cib + ci8) * 3 + kh];
        }
        // k1 part (taps 3..6)
        for (int i = tid; i < CICHUNK * 4 * COUT; i += 256) {
            int co  = i / (CICHUNK * 4);
            int rr  = i % (CICHUNK * 4);
            int ci8 = rr / 4;
            int kq  = rr % 4;
            wl[ci8][3 + kq][co] = k1[(co * CIN + cib + ci8) * 4 + kq];
        }
        __syncthreads();

        for (int ci8 = 0; ci8 < CICHUNK; ++ci8) {
            // x stencil for this ci: xs rows r..r+2, xs cols c0..c0+5
            // (xs col c maps to global w = w0 - 1 + c)
            float xv[3][6];
            #pragma unroll
            for (int d = 0; d < 3; ++d)
                #pragma unroll
                for (int cc = 0; cc < 6; ++cc)
                    xv[d][cc] = xs[cib + ci8][r + d][c0 + cc];

            #pragma unroll
            for (int tap = 0; tap < 7; ++tap) {
                float wv[8];
                #pragma unroll
                for (int j = 0; j < 8; ++j)
                    wv[j] = wl[ci8][tap][co0 + j];
                #pragma unroll
                for (int k = 0; k < 4; ++k) {
                    // global w = w0 + c0 + k; w0,c0 even -> parity = k&1
                    const int par = k & 1;
                    float xval;
                    if (tap < 3)       xval = xv[tap][k + 1];      // vertical, col w
                    else if (tap == 3) xval = xv[par][k];          // (kh0,kw0) col w-1
                    else if (tap == 4) xval = xv[par][k + 2];      // (kh0,kw1) col w+1
                    else if (tap == 5) xval = xv[1 + par][k];      // (kh1,kw0) col w-1
                    else               xval = xv[1 + par][k + 2];  // (kh1,kw1) col w+1
                    #pragma unroll
                    for (int j = 0; j < 8; ++j)
                        acc[j][k] = fmaf(wv[j], xval, acc[j][k]);
                }
            }
        }
        __syncthreads();
    }

    // ---- epilogue: add bias, store ----
    const int gh = h0 + r;
    #pragma unroll
    for (int j = 0; j < 8; ++j) {
        float bv = bias[co0 + j];
        float* op = out + (((size_t)b * COUT + (co0 + j)) * HH + gh) * WW + w0 + c0;
        #pragma unroll
        for (int k = 0; k < 4; ++k)
            op[k] = acc[j][k] + bv;
    }
}

extern "C" void kernel_launch(void* const* d_in, const int* in_sizes, int n_in,
                              void* d_out, int out_size, void* d_ws, size_t ws_size,
                              hipStream_t stream) {
    const float* x    = (const float*)d_in[0];
    const float* k0   = (const float*)d_in[1];
    const float* k1   = (const float*)d_in[2];
    const float* bias = (const float*)d_in[3];
    float* out        = (float*)d_out;

    dim3 grid(WW / TILE, HH / TILE, 8);   // (32, 32, 8)
    hexconv_fp32<<<grid, 256, 0, stream>>>(x, k0, k1, bias, out);
}

// Round 2
// 402.818 us; speedup vs baseline: 4.0428x; 4.0428x over previous
//
#include <hip/hip_runtime.h>
#include <hip/hip_bf16.h>

// hexagdly conv2d as implicit GEMM with bf16 MFMA.
// out[b,co,h,w] = bias[co]
//   + sum_ci sum_{t=0..2} x[b,ci,h-1+t,w]   * k0[co,ci,t]
//   + (w even) sum_ci sum_{kh,kw} x[b,ci,h-1+kh,w-1+2kw] * k1[co,ci,kh,kw]
//   + (w odd)  sum_ci sum_{kh,kw} x[b,ci,h+kh,  w-1+2kw] * k1[co,ci,kh,kw]

#define CIN  64
#define COUT 128
#define HH   256
#define WW   256
#define TH   8
#define TW   32
#define XR   10   // TH + 2 halo rows
#define XC   34   // TW + 2 halo cols

typedef __attribute__((ext_vector_type(8))) short short8;
typedef __attribute__((ext_vector_type(4))) float f32x4;

static __device__ __forceinline__ unsigned short f2bf(float v) {
    __hip_bfloat16 h = __float2bfloat16(v);
    return __builtin_bit_cast(unsigned short, h);
}

__global__ __launch_bounds__(512, 4)
void hexconv_mfma(const float* __restrict__ x,
                  const float* __restrict__ k0,
                  const float* __restrict__ k1,
                  const float* __restrict__ bias,
                  float* __restrict__ out)
{
    // x tile, bf16, ci-contiguous, XOR-swizzled by (col&7): elem ^= (col&7)*8
    __shared__ alignas(16) unsigned short xs[XR * XC * CIN];      // 43520 B
    // per-tap weight buffers [co][ci], swizzled by (co&7), double-buffered
    __shared__ alignas(16) unsigned short wtb[2][COUT * CIN];     // 32768 B
    __shared__ float bias_lds[COUT];

    const int tid = threadIdx.x;
    const int b   = blockIdx.z;
    const int h0  = blockIdx.y * TH;
    const int w0  = blockIdx.x * TW;   // even

    if (tid < COUT) bias_lds[tid] = bias[tid];

    // ---------- stage x tile: fp32 -> bf16, transpose to ci-contiguous ----------
    {
        const float* xb = x + (size_t)b * CIN * HH * WW;
        const int c = tid & 31;          // col 0..31 of the 32 interior cols
        const int g = tid >> 5;          // 0..15
        for (int p = g; p < XR * 32; p += 16) {      // 320 (row, ci-pair) units
            const int cip = p & 31;
            const int row = p >> 5;                  // 0..9
            const int ci  = cip * 2;
            const int gh  = h0 - 1 + row;
            float v0 = 0.f, v1 = 0.f;
            if ((unsigned)gh < HH) {
                const float* pr = xb + ((size_t)ci * HH + gh) * WW + w0 + c;
                v0 = pr[0];
                v1 = pr[HH * WW];
            }
            unsigned int pk = (unsigned int)f2bf(v0) | ((unsigned int)f2bf(v1) << 16);
            const int col = c + 1;
            const int e = ((row * XC + col) * CIN + ci) ^ ((col & 7) * 8);
            *(unsigned int*)&xs[e] = pk;
        }
        // halo cols: col 0 (gw = w0-1) and col 33 (gw = w0+32)
        for (int i = tid; i < 2 * XR * CIN; i += 512) {
            const int side = (i >= XR * CIN) ? 1 : 0;
            const int rem  = i - side * XR * CIN;
            const int row  = rem >> 6;
            const int ci   = rem & 63;
            const int col  = side ? (XC - 1) : 0;
            const int gh   = h0 - 1 + row;
            const int gw   = side ? (w0 + TW) : (w0 - 1);
            float v = 0.f;
            if ((unsigned)gh < HH && (unsigned)gw < WW)
                v = xb[((size_t)ci * HH + gh) * WW + gw];
            const int e = ((row * XC + col) * CIN + ci) ^ ((col & 7) * 8);
            xs[e] = f2bf(v);
        }
    }

    // ---------- stage tap-0 weights into wtb[0] ----------
    {
        #pragma unroll
        for (int i = 0; i < 2; ++i) {
            const int f  = tid * 2 + i;      // 0..1023 = 128 co x 8 ci-blocks
            const int co = f >> 3;
            const int ci = (f & 7) * 8;
            short8 wv;
            #pragma unroll
            for (int j = 0; j < 8; ++j)
                wv[j] = (short)f2bf(k0[(co * CIN + ci + j) * 3 + 0]);
            const int e = (co * CIN + ci) ^ ((co & 7) * 8);
            *(short8*)&wtb[0][e] = wv;
        }
    }

    __syncthreads();

    // ---------- compute: wave tiling ----------
    const int lane = tid & 63;
    const int wid  = tid >> 6;       // 8 waves
    const int wm   = wid & 1;        // co block of 64
    const int wn   = wid >> 1;       // 2 h-rows of 32 cols each
    const int c15  = lane & 15;
    const int q8   = (lane >> 4) * 8;
    const int par  = lane & 1;       // parity of output column (w0 even)

    const int aBase = (wm * 64 + c15) * CIN + q8;
    const int swzA  = (c15 & 7) * 8;

    f32x4 acc[4][4];
    #pragma unroll
    for (int mi = 0; mi < 4; ++mi)
        #pragma unroll
        for (int ni = 0; ni < 4; ++ni)
            acc[mi][ni] = (f32x4)0.0f;

    for (int tap = 0; tap < 7; ++tap) {
        const unsigned short* wc = wtb[tap & 1];

        // B-operand address parameters for this tap
        int R0, P, C0;
        if (tap < 3) { R0 = tap; P = 0; C0 = 1; }                   // vertical 3x1
        else { R0 = (tap - 3) >> 1; P = 1; C0 = ((tap - 3) & 1) * 2; } // hex 2x2
        const int colb  = c15 + C0;                 // + chalf*16 later (&7 invariant)
        const int swzB  = (colb & 7) * 8;
        const int bBase = ((wn * 2 + R0 + P * par) * XC + colb) * CIN + q8;

        #pragma unroll
        for (int ci0 = 0; ci0 < CIN; ci0 += 32) {
            short8 af[4];
            #pragma unroll
            for (int mi = 0; mi < 4; ++mi)
                af[mi] = *(const short8*)&wc[(aBase + mi * 16 * CIN + ci0) ^ swzA];
            #pragma unroll
            for (int ni = 0; ni < 4; ++ni) {
                const int hr = ni >> 1, chalf = ni & 1;
                const int e = (bBase + hr * (XC * CIN) + chalf * (16 * CIN) + ci0) ^ swzB;
                short8 bf = *(const short8*)&xs[e];
                #pragma unroll
                for (int mi = 0; mi < 4; ++mi)
                    acc[mi][ni] = __builtin_amdgcn_mfma_f32_16x16x32_bf16(
                        af[mi], bf, acc[mi][ni], 0, 0, 0);
            }
        }

        // stage next tap's weights into the other buffer
        if (tap < 6) {
            const int t   = tap + 1;
            const int buf = t & 1;
            #pragma unroll
            for (int i = 0; i < 2; ++i) {
                const int f  = tid * 2 + i;
                const int co = f >> 3;
                const int ci = (f & 7) * 8;
                short8 wvv;
                if (t < 3) {
                    #pragma unroll
                    for (int j = 0; j < 8; ++j)
                        wvv[j] = (short)f2bf(k0[(co * CIN + ci + j) * 3 + t]);
                } else {
                    #pragma unroll
                    for (int j = 0; j < 8; ++j)
                        wvv[j] = (short)f2bf(k1[(co * CIN + ci + j) * 4 + (t - 3)]);
                }
                const int e = (co * CIN + ci) ^ ((co & 7) * 8);
                *(short8*)&wtb[buf][e] = wvv;
            }
        }
        __syncthreads();
    }

    // ---------- epilogue: bias + store ----------
    // C/D layout (16x16): col = lane&15, row = (lane>>4)*4 + reg
    #pragma unroll
    for (int mi = 0; mi < 4; ++mi) {
        #pragma unroll
        for (int ni = 0; ni < 4; ++ni) {
            const int hr = ni >> 1, chalf = ni & 1;
            const int w = w0 + chalf * 16 + c15;
            const int h = h0 + wn * 2 + hr;
            #pragma unroll
            for (int r = 0; r < 4; ++r) {
                const int co = wm * 64 + mi * 16 + (lane >> 4) * 4 + r;
                out[(((size_t)b * COUT + co) * HH + h) * WW + w] =
                    acc[mi][ni][r] + bias_lds[co];
            }
        }
    }
}

extern "C" void kernel_launch(void* const* d_in, const int* in_sizes, int n_in,
                              void* d_out, int out_size, void* d_ws, size_t ws_size,
                              hipStream_t stream) {
    const float* x    = (const float*)d_in[0];
    const float* k0   = (const float*)d_in[1];
    const float* k1   = (const float*)d_in[2];
    const float* bias = (const float*)d_in[3];
    float* out        = (float*)d_out;

    dim3 grid(WW / TW, HH / TH, 8);   // (8, 32, 8) = 2048 blocks
    hexconv_mfma<<<grid, 512, 0, stream>>>(x, k0, k1, bias, out);
}

// Round 3
// 357.702 us; speedup vs baseline: 4.5527x; 1.1261x over previous
//
#include <hip/hip_runtime.h>
#include <hip/hip_bf16.h>

// hexagdly conv2d as implicit GEMM with bf16 MFMA.
// out[b,co,h,w] = bias[co]
//   + sum_ci sum_{t=0..2} x[b,ci,h-1+t,w]   * k0[co,ci,t]
//   + (w even) sum_ci sum_{kh,kw} x[b,ci,h-1+kh,w-1+2kw] * k1[co,ci,kh,kw]
//   + (w odd)  sum_ci sum_{kh,kw} x[b,ci,h+kh,  w-1+2kw] * k1[co,ci,kh,kw]

#define CIN  64
#define COUT 128
#define HH   256
#define WW   256
#define TH   8
#define TW   32
#define XR   10   // TH + 2 halo rows
#define XC   34   // TW + 2 halo cols

typedef __attribute__((ext_vector_type(8))) short short8;
typedef __attribute__((ext_vector_type(4))) float f32x4;

static __device__ __forceinline__ unsigned short f2bf(float v) {
    __hip_bfloat16 h = __float2bfloat16(v);
    return __builtin_bit_cast(unsigned short, h);
}

#define XS_BYTES   (XR * XC * CIN * 2)          // 43520
#define WTB_OFF    XS_BYTES
#define SMEM_BYTES (XS_BYTES + 2 * COUT * CIN * 2)  // 43520 + 32768 = 76288
#define OT_STRIDE  33                            // padded w row (floats)

__global__ __launch_bounds__(512, 4)
void hexconv_mfma(const float* __restrict__ x,
                  const float* __restrict__ k0,
                  const float* __restrict__ k1,
                  const float* __restrict__ bias,
                  float* __restrict__ out)
{
    __shared__ alignas(16) char smem[SMEM_BYTES];
    __shared__ float bias_lds[COUT];
    unsigned short* xs  = (unsigned short*)smem;                // compute phase
    unsigned short* wtb = (unsigned short*)(smem + WTB_OFF);    // compute phase
    float*          ot  = (float*)smem;                         // epilogue phase

    const int tid = threadIdx.x;

    // XCD-aware swizzle: nwg = 2048 = 8 XCD x 256; each XCD gets one batch image
    const int wg = (blockIdx.x & 7) * 256 + (blockIdx.x >> 3);
    const int bx = wg & 7;            // w tile 0..7
    const int by = (wg >> 3) & 31;    // h tile 0..31
    const int b  = wg >> 8;           // batch 0..7

    const int h0 = by * TH;
    const int w0 = bx * TW;           // even

    if (tid < COUT) bias_lds[tid] = bias[tid];

    // ---------- stage x tile: fp32 -> bf16, transpose to ci-contiguous ----------
    {
        const float* xb = x + (size_t)b * CIN * HH * WW;
        const int c = tid & 31;          // col 0..31 of the 32 interior cols
        const int g = tid >> 5;          // 0..15
        for (int p = g; p < XR * 32; p += 16) {      // 320 (row, ci-pair) units
            const int cip = p & 31;
            const int row = p >> 5;                  // 0..9
            const int ci  = cip * 2;
            const int gh  = h0 - 1 + row;
            float v0 = 0.f, v1 = 0.f;
            if ((unsigned)gh < HH) {
                const float* pr = xb + ((size_t)ci * HH + gh) * WW + w0 + c;
                v0 = pr[0];
                v1 = pr[HH * WW];
            }
            unsigned int pk = (unsigned int)f2bf(v0) | ((unsigned int)f2bf(v1) << 16);
            const int col = c + 1;
            const int e = ((row * XC + col) * CIN + ci) ^ ((col & 7) * 8);
            *(unsigned int*)&xs[e] = pk;
        }
        // halo cols: col 0 (gw = w0-1) and col 33 (gw = w0+32)
        for (int i = tid; i < 2 * XR * CIN; i += 512) {
            const int side = (i >= XR * CIN) ? 1 : 0;
            const int rem  = i - side * XR * CIN;
            const int row  = rem >> 6;
            const int ci   = rem & 63;
            const int col  = side ? (XC - 1) : 0;
            const int gh   = h0 - 1 + row;
            const int gw   = side ? (w0 + TW) : (w0 - 1);
            float v = 0.f;
            if ((unsigned)gh < HH && (unsigned)gw < WW)
                v = xb[((size_t)ci * HH + gh) * WW + gw];
            const int e = ((row * XC + col) * CIN + ci) ^ ((col & 7) * 8);
            xs[e] = f2bf(v);
        }
    }

    // ---------- stage tap-0 weights into wtb buf 0 ----------
    {
        #pragma unroll
        for (int i = 0; i < 2; ++i) {
            const int f  = tid * 2 + i;      // 0..1023 = 128 co x 8 ci-blocks
            const int co = f >> 3;
            const int ci = (f & 7) * 8;
            short8 wv;
            #pragma unroll
            for (int j = 0; j < 8; ++j)
                wv[j] = (short)f2bf(k0[(co * CIN + ci + j) * 3 + 0]);
            const int e = (co * CIN + ci) ^ ((co & 7) * 8);
            *(short8*)&wtb[e] = wv;
        }
    }

    __syncthreads();

    // ---------- compute: wave tiling ----------
    const int lane = tid & 63;
    const int wid  = tid >> 6;       // 8 waves
    const int wm   = wid & 1;        // co block of 64
    const int wn   = wid >> 1;       // 2 h-rows of 32 cols each
    const int c15  = lane & 15;
    const int q8   = (lane >> 4) * 8;
    const int par  = lane & 1;       // parity of output column (w0 even)

    const int aBase = (wm * 64 + c15) * CIN + q8;
    const int swzA  = (c15 & 7) * 8;

    f32x4 acc[4][4];
    #pragma unroll
    for (int mi = 0; mi < 4; ++mi)
        #pragma unroll
        for (int ni = 0; ni < 4; ++ni)
            acc[mi][ni] = (f32x4)0.0f;

    for (int tap = 0; tap < 7; ++tap) {
        const unsigned short* wc = wtb + (tap & 1) * (COUT * CIN);

        // B-operand address parameters for this tap
        int R0, P, C0;
        if (tap < 3) { R0 = tap; P = 0; C0 = 1; }                   // vertical 3x1
        else { R0 = (tap - 3) >> 1; P = 1; C0 = ((tap - 3) & 1) * 2; } // hex 2x2
        const int colb  = c15 + C0;                 // + chalf*16 later (&7 invariant)
        const int swzB  = (colb & 7) * 8;
        const int bBase = ((wn * 2 + R0 + P * par) * XC + colb) * CIN + q8;

        #pragma unroll
        for (int ci0 = 0; ci0 < CIN; ci0 += 32) {
            short8 af[4];
            #pragma unroll
            for (int mi = 0; mi < 4; ++mi)
                af[mi] = *(const short8*)&wc[(aBase + mi * 16 * CIN + ci0) ^ swzA];
            #pragma unroll
            for (int ni = 0; ni < 4; ++ni) {
                const int hr = ni >> 1, chalf = ni & 1;
                const int e = (bBase + hr * (XC * CIN) + chalf * (16 * CIN) + ci0) ^ swzB;
                short8 bf = *(const short8*)&xs[e];
                #pragma unroll
                for (int mi = 0; mi < 4; ++mi)
                    acc[mi][ni] = __builtin_amdgcn_mfma_f32_16x16x32_bf16(
                        af[mi], bf, acc[mi][ni], 0, 0, 0);
            }
        }

        // stage next tap's weights into the other buffer
        if (tap < 6) {
            const int t   = tap + 1;
            const int buf = t & 1;
            #pragma unroll
            for (int i = 0; i < 2; ++i) {
                const int f  = tid * 2 + i;
                const int co = f >> 3;
                const int ci = (f & 7) * 8;
                short8 wvv;
                if (t < 3) {
                    #pragma unroll
                    for (int j = 0; j < 8; ++j)
                        wvv[j] = (short)f2bf(k0[(co * CIN + ci + j) * 3 + t]);
                } else {
                    #pragma unroll
                    for (int j = 0; j < 8; ++j)
                        wvv[j] = (short)f2bf(k1[(co * CIN + ci + j) * 4 + (t - 3)]);
                }
                const int e = (co * CIN + ci) ^ ((co & 7) * 8);
                *(short8*)&wtb[buf * (COUT * CIN) + e] = wvv;
            }
        }
        __syncthreads();
    }

    // ---------- epilogue: LDS bounce for fully-coalesced 128B row stores ----------
    // C/D layout (16x16): col = lane&15, row = (lane>>4)*4 + reg
    #pragma unroll
    for (int p = 0; p < 2; ++p) {
        if (wm == p) {
            #pragma unroll
            for (int mi = 0; mi < 4; ++mi) {
                #pragma unroll
                for (int ni = 0; ni < 4; ++ni) {
                    const int hh   = wn * 2 + (ni >> 1);
                    const int wloc = (ni & 1) * 16 + c15;
                    #pragma unroll
                    for (int r = 0; r < 4; ++r) {
                        const int col = mi * 16 + (lane >> 4) * 4 + r;   // local co 0..63
                        ot[(col * TH + hh) * OT_STRIDE + wloc] =
                            acc[mi][ni][r] + bias_lds[p * 64 + col];
                    }
                }
            }
        }
        __syncthreads();
        // 512 threads x 8 iters = 4096 float4 = 64co x 8h x 32w
        #pragma unroll
        for (int it = 0; it < 8; ++it) {
            const int col = it * 8 + (tid >> 6);     // local co
            const int hh  = (tid >> 3) & 7;
            const int w4  = (tid & 7) * 4;
            const float* src = &ot[(col * TH + hh) * OT_STRIDE + w4];
            f32x4 v = { src[0], src[1], src[2], src[3] };
            *(f32x4*)&out[(((size_t)b * COUT + p * 64 + col) * HH + h0 + hh) * WW + w0 + w4] = v;
        }
        if (p == 0) __syncthreads();
    }
}

extern "C" void kernel_launch(void* const* d_in, const int* in_sizes, int n_in,
                              void* d_out, int out_size, void* d_ws, size_t ws_size,
                              hipStream_t stream) {
    const float* x    = (const float*)d_in[0];
    const float* k0   = (const float*)d_in[1];
    const float* k1   = (const float*)d_in[2];
    const float* bias = (const float*)d_in[3];
    float* out        = (float*)d_out;

    hexconv_mfma<<<dim3(2048, 1, 1), 512, 0, stream>>>(x, k0, k1, bias, out);
}

// Round 4
// 113.688 us; speedup vs baseline: 14.3245x; 3.1463x over previous
//
#include <hip/hip_runtime.h>
#include <hip/hip_bf16.h>

// hexagdly conv2d as implicit GEMM with bf16 MFMA.
// out[b,co,h,w] = bias[co]
//   + sum_ci sum_{t=0..2} x[b,ci,h-1+t,w]   * k0[co,ci,t]
//   + (w even) sum_ci sum_{kh,kw} x[b,ci,h-1+kh,w-1+2kw] * k1[co,ci,kh,kw]
//   + (w odd)  sum_ci sum_{kh,kw} x[b,ci,h+kh,  w-1+2kw] * k1[co,ci,kh,kw]

#define CIN  64
#define COUT 128
#define HH   256
#define WW   256
#define TH   8
#define TW   32
#define XR   10   // TH + 2 halo rows
#define XC   34   // TW + 2 halo cols

typedef __attribute__((ext_vector_type(8))) short short8;
typedef __attribute__((ext_vector_type(4))) float f32x4;

static __device__ __forceinline__ unsigned short f2bf(float v) {
    __hip_bfloat16 h = __float2bfloat16(v);
    return __builtin_bit_cast(unsigned short, h);
}

typedef __attribute__((address_space(1))) const unsigned int asg_u32;
typedef __attribute__((address_space(3))) unsigned int asl_u32;
static __device__ __forceinline__ void gl2lds16(const void* g, void* l) {
    __builtin_amdgcn_global_load_lds((asg_u32*)g, (asl_u32*)l, 16, 0, 0);
}

#define XS_BYTES   (XR * XC * CIN * 2)               // 43520
#define WTB_OFF    XS_BYTES
#define SMEM_BYTES (XS_BYTES + 2 * COUT * CIN * 2)   // 43520 + 32768 = 76288
#define OT_STRIDE  33                                // padded w row (floats)
#define WTAP       (COUT * CIN)                      // halfwords per tap = 8192

// ---------- pre-kernel: k0/k1 -> bf16 [tap][co][ci], pre-swizzled ----------
__global__ __launch_bounds__(512)
void prep_weights(const float* __restrict__ k0, const float* __restrict__ k1,
                  unsigned short* __restrict__ wsw)
{
    const int idx = blockIdx.x * 512 + threadIdx.x;   // 0..7167
    if (idx >= 7 * COUT * 8) return;
    const int t   = idx >> 10;         // tap 0..6
    const int co  = (idx >> 3) & 127;
    const int ci0 = (idx & 7) * 8;
    short8 wv;
    #pragma unroll
    for (int j = 0; j < 8; ++j) {
        const int ci = ci0 + j;
        float v = (t < 3) ? k0[(co * CIN + ci) * 3 + t]
                          : k1[(co * CIN + ci) * 4 + (t - 3)];
        wv[j] = (short)f2bf(v);
    }
    const int e = (co * CIN + ci0) ^ ((co & 7) * 8);
    *(short8*)&wsw[t * WTAP + e] = wv;
}

__global__ __launch_bounds__(512, 4)
void hexconv_mfma(const float* __restrict__ x,
                  const unsigned short* __restrict__ wsw,
                  const float* __restrict__ bias,
                  float* __restrict__ out)
{
    __shared__ alignas(16) char smem[SMEM_BYTES];
    __shared__ float bias_lds[COUT];
    unsigned short* xs  = (unsigned short*)smem;                // compute phase
    unsigned short* wtb = (unsigned short*)(smem + WTB_OFF);    // compute phase
    float*          ot  = (float*)smem;                         // epilogue phase

    const int tid  = threadIdx.x;
    const int lane = tid & 63;
    const int wid  = tid >> 6;       // 8 waves

    // XCD-aware swizzle: nwg = 2048 = 8 XCD x 256; each XCD gets one batch image
    const int wg = (blockIdx.x & 7) * 256 + (blockIdx.x >> 3);
    const int bx = wg & 7;            // w tile 0..7
    const int by = (wg >> 3) & 31;    // h tile 0..31
    const int b  = wg >> 8;           // batch 0..7

    const int h0 = by * TH;
    const int w0 = bx * TW;           // even

    // ---- weight staging via async global->LDS (linear dest, pre-swizzled src) ----
    // wave wid owns halfwords [wid*1024, wid*1024+1024) of the 8192-halfword tap
    auto stage_tap = [&](int t, int buf) {
        const unsigned short* s0 = wsw + t * WTAP + wid * 1024;
        unsigned short* d0 = wtb + buf * WTAP + wid * 1024;
        gl2lds16(s0 + lane * 8, d0);
        gl2lds16(s0 + 512 + lane * 8, d0 + 512);
    };

    stage_tap(0, 0);   // tap 0 -> buffer 0, overlaps x staging

    if (tid < COUT) bias_lds[tid] = bias[tid];

    // ---------- stage x tile: fp32 -> bf16, transpose to ci-contiguous ----------
    {
        const float* xb = x + (size_t)b * CIN * HH * WW;
        const int c = tid & 31;          // col 0..31 of the 32 interior cols
        const int g = tid >> 5;          // 0..15
        for (int p = g; p < XR * 32; p += 16) {      // 320 (row, ci-pair) units
            const int cip = p & 31;
            const int row = p >> 5;                  // 0..9
            const int ci  = cip * 2;
            const int gh  = h0 - 1 + row;
            float v0 = 0.f, v1 = 0.f;
            if ((unsigned)gh < HH) {
                const float* pr = xb + ((size_t)ci * HH + gh) * WW + w0 + c;
                v0 = pr[0];
                v1 = pr[HH * WW];
            }
            unsigned int pk = (unsigned int)f2bf(v0) | ((unsigned int)f2bf(v1) << 16);
            const int col = c + 1;
            const int e = ((row * XC + col) * CIN + ci) ^ ((col & 7) * 8);
            *(unsigned int*)&xs[e] = pk;
        }
        // halo cols: col 0 (gw = w0-1) and col 33 (gw = w0+32)
        for (int i = tid; i < 2 * XR * CIN; i += 512) {
            const int side = (i >= XR * CIN) ? 1 : 0;
            const int rem  = i - side * XR * CIN;
            const int row  = rem >> 6;
            const int ci   = rem & 63;
            const int col  = side ? (XC - 1) : 0;
            const int gh   = h0 - 1 + row;
            const int gw   = side ? (w0 + TW) : (w0 - 1);
            float v = 0.f;
            if ((unsigned)gh < HH && (unsigned)gw < WW)
                v = xb[((size_t)ci * HH + gh) * WW + gw];
            const int e = ((row * XC + col) * CIN + ci) ^ ((col & 7) * 8);
            xs[e] = f2bf(v);
        }
    }

    __syncthreads();   // drains vmcnt -> tap 0 weights + x tile ready

    // ---------- compute: wave tiling ----------
    const int wm   = wid & 1;        // co block of 64
    const int wn   = wid >> 1;       // 2 h-rows of 32 cols each
    const int c15  = lane & 15;
    const int q8   = (lane >> 4) * 8;
    const int par  = lane & 1;       // parity of output column (w0 even)

    const int aBase = (wm * 64 + c15) * CIN + q8;
    const int swzA  = (c15 & 7) * 8;

    f32x4 acc[4][4];
    #pragma unroll
    for (int mi = 0; mi < 4; ++mi)
        #pragma unroll
        for (int ni = 0; ni < 4; ++ni)
            acc[mi][ni] = (f32x4)0.0f;

    for (int tap = 0; tap < 7; ++tap) {
        if (tap < 6) stage_tap(tap + 1, (tap + 1) & 1);   // overlap with MFMA below

        const unsigned short* wc = wtb + (tap & 1) * WTAP;

        // B-operand address parameters for this tap
        int R0, P, C0;
        if (tap < 3) { R0 = tap; P = 0; C0 = 1; }                   // vertical 3x1
        else { R0 = (tap - 3) >> 1; P = 1; C0 = ((tap - 3) & 1) * 2; } // hex 2x2
        const int colb  = c15 + C0;                 // + chalf*16 later (&7 invariant)
        const int swzB  = (colb & 7) * 8;
        const int bBase = ((wn * 2 + R0 + P * par) * XC + colb) * CIN + q8;

        #pragma unroll
        for (int ci0 = 0; ci0 < CIN; ci0 += 32) {
            short8 af[4];
            #pragma unroll
            for (int mi = 0; mi < 4; ++mi)
                af[mi] = *(const short8*)&wc[(aBase + mi * 16 * CIN + ci0) ^ swzA];
            #pragma unroll
            for (int ni = 0; ni < 4; ++ni) {
                const int hr = ni >> 1, chalf = ni & 1;
                const int e = (bBase + hr * (XC * CIN) + chalf * (16 * CIN) + ci0) ^ swzB;
                short8 bf = *(const short8*)&xs[e];
                #pragma unroll
                for (int mi = 0; mi < 4; ++mi)
                    acc[mi][ni] = __builtin_amdgcn_mfma_f32_16x16x32_bf16(
                        af[mi], bf, acc[mi][ni], 0, 0, 0);
            }
        }
        __syncthreads();   // vmcnt(0) drain makes next tap's weights visible
    }

    // ---------- epilogue: LDS bounce for fully-coalesced 128B row stores ----------
    // C/D layout (16x16): col = lane&15, row = (lane>>4)*4 + reg
    #pragma unroll
    for (int p = 0; p < 2; ++p) {
        if (wm == p) {
            #pragma unroll
            for (int mi = 0; mi < 4; ++mi) {
                #pragma unroll
                for (int ni = 0; ni < 4; ++ni) {
                    const int hh   = wn * 2 + (ni >> 1);
                    const int wloc = (ni & 1) * 16 + c15;
                    #pragma unroll
                    for (int r = 0; r < 4; ++r) {
                        const int col = mi * 16 + (lane >> 4) * 4 + r;   // local co 0..63
                        ot[(col * TH + hh) * OT_STRIDE + wloc] =
                            acc[mi][ni][r] + bias_lds[p * 64 + col];
                    }
                }
            }
        }
        __syncthreads();
        // 512 threads x 8 iters = 4096 float4 = 64co x 8h x 32w
        #pragma unroll
        for (int it = 0; it < 8; ++it) {
            const int col = it * 8 + (tid >> 6);     // local co
            const int hh  = (tid >> 3) & 7;
            const int w4  = (tid & 7) * 4;
            const float* src = &ot[(col * TH + hh) * OT_STRIDE + w4];
            f32x4 v = { src[0], src[1], src[2], src[3] };
            __builtin_nontemporal_store(v,
                (f32x4*)&out[(((size_t)b * COUT + p * 64 + col) * HH + h0 + hh) * WW + w0 + w4]);
        }
        if (p == 0) __syncthreads();
    }
}

extern "C" void kernel_launch(void* const* d_in, const int* in_sizes, int n_in,
                              void* d_out, int out_size, void* d_ws, size_t ws_size,
                              hipStream_t stream) {
    const float* x    = (const float*)d_in[0];
    const float* k0   = (const float*)d_in[1];
    const float* k1   = (const float*)d_in[2];
    const float* bias = (const float*)d_in[3];
    float* out        = (float*)d_out;
    unsigned short* wsw = (unsigned short*)d_ws;   // 7*128*64*2 = 114688 B

    prep_weights<<<dim3(14, 1, 1), 512, 0, stream>>>(k0, k1, wsw);
    hexconv_mfma<<<dim3(2048, 1, 1), 512, 0, stream>>>(x, wsw, bias, out);
}

// Round 5
// 98.415 us; speedup vs baseline: 16.5476x; 1.1552x over previous
//
#include <hip/hip_runtime.h>
#include <hip/hip_bf16.h>

// hexagdly conv2d as implicit GEMM with bf16 MFMA.
// out[b,co,h,w] = bias[co]
//   + sum_ci sum_{t=0..2} x[b,ci,h-1+t,w]   * k0[co,ci,t]
//   + (w even) sum_ci sum_{kh,kw} x[b,ci,h-1+kh,w-1+2kw] * k1[co,ci,kh,kw]
//   + (w odd)  sum_ci sum_{kh,kw} x[b,ci,h+kh,  w-1+2kw] * k1[co,ci,kh,kw]

#define CIN  64
#define COUT 128
#define HH   256
#define WW   256
#define TH   8
#define TW   32
#define XR   10   // TH + 2 halo rows
#define XC   34   // TW + 2 halo cols

typedef __attribute__((ext_vector_type(8))) short short8;
typedef __attribute__((ext_vector_type(4))) float f32x4;

static __device__ __forceinline__ unsigned short f2bf(float v) {
    __hip_bfloat16 h = __float2bfloat16(v);
    return __builtin_bit_cast(unsigned short, h);
}

typedef __attribute__((address_space(1))) const unsigned int asg_u32;
typedef __attribute__((address_space(3))) unsigned int asl_u32;
static __device__ __forceinline__ void gl2lds16(const void* g, void* l) {
    __builtin_amdgcn_global_load_lds((asg_u32*)g, (asl_u32*)l, 16, 0, 0);
}

#define XS_BYTES   (XR * XC * CIN * 2)               // 43520
#define WTB_OFF    XS_BYTES
#define SMEM_BYTES (XS_BYTES + 2 * COUT * CIN * 2)   // 43520 + 32768 = 76288
#define OT_STRIDE  33                                // padded w row (floats)
#define WTAP       (COUT * CIN)                      // halfwords per tap = 8192

// ---------- pre-kernel: k0/k1 -> bf16 [tap][co][ci], pre-swizzled ----------
__global__ __launch_bounds__(512)
void prep_weights(const float* __restrict__ k0, const float* __restrict__ k1,
                  unsigned short* __restrict__ wsw)
{
    const int idx = blockIdx.x * 512 + threadIdx.x;   // 0..7167
    if (idx >= 7 * COUT * 8) return;
    const int t   = idx >> 10;         // tap 0..6
    const int co  = (idx >> 3) & 127;
    const int ci0 = (idx & 7) * 8;
    short8 wv;
    #pragma unroll
    for (int j = 0; j < 8; ++j) {
        const int ci = ci0 + j;
        float v = (t < 3) ? k0[(co * CIN + ci) * 3 + t]
                          : k1[(co * CIN + ci) * 4 + (t - 3)];
        wv[j] = (short)f2bf(v);
    }
    const int e = (co * CIN + ci0) ^ ((co & 7) * 8);
    *(short8*)&wsw[t * WTAP + e] = wv;
}

__global__ __launch_bounds__(512, 4)
void hexconv_mfma(const float* __restrict__ x,
                  const unsigned short* __restrict__ wsw,
                  const float* __restrict__ bias,
                  float* __restrict__ out)
{
    __shared__ alignas(16) char smem[SMEM_BYTES];
    __shared__ float bias_lds[COUT];
    unsigned short* xs  = (unsigned short*)smem;                // compute phase
    unsigned short* wtb = (unsigned short*)(smem + WTB_OFF);    // compute phase
    float*          ot  = (float*)smem;                         // epilogue phase

    const int tid  = threadIdx.x;
    const int lane = tid & 63;
    const int wid  = tid >> 6;       // 8 waves

    // XCD-aware swizzle: nwg = 2048 = 8 XCD x 256; each XCD gets one batch image
    const int wg = (blockIdx.x & 7) * 256 + (blockIdx.x >> 3);
    const int bx = wg & 7;            // w tile 0..7
    const int by = (wg >> 3) & 31;    // h tile 0..31
    const int b  = wg >> 8;           // batch 0..7

    const int h0 = by * TH;
    const int w0 = bx * TW;           // even

    // ---- weight staging via async global->LDS (linear dest, pre-swizzled src) ----
    // wave wid owns halfwords [wid*1024, wid*1024+1024) of the 8192-halfword tap
    auto stage_tap = [&](int t, int buf) {
        const unsigned short* s0 = wsw + t * WTAP + wid * 1024;
        unsigned short* d0 = wtb + buf * WTAP + wid * 1024;
        gl2lds16(s0 + lane * 8, d0);
        gl2lds16(s0 + 512 + lane * 8, d0 + 512);
    };

    stage_tap(0, 0);   // tap 0 -> buffer 0, overlaps x staging

    if (tid < COUT) bias_lds[tid] = bias[tid];

    // ---------- stage x tile: fp32 -> bf16 (vectorized), ci-contiguous ----------
    {
        const float* xb = x + (size_t)b * CIN * HH * WW;
        // interior cols 1..32 (gw = w0..w0+31): float4 over 4 w, 2 ci per unit
        const int cg = tid & 7;              // col group: gw = w0 + 4*cg + k
        const int u0 = tid >> 3;             // unit: (row, ci-pair)
        #pragma unroll
        for (int it = 0; it < 5; ++it) {
            const int u   = u0 + it * 64;    // 0..319
            const int row = u >> 5;          // 0..9
            const int ci  = (u & 31) * 2;
            const int gh  = h0 - 1 + row;
            f32x4 a = (f32x4)0.0f, c = (f32x4)0.0f;
            if ((unsigned)gh < HH) {
                const float* pb = xb + ((size_t)ci * HH + gh) * WW + w0 + 4 * cg;
                a = *(const f32x4*)pb;
                c = *(const f32x4*)(pb + HH * WW);
            }
            #pragma unroll
            for (int k = 0; k < 4; ++k) {
                const int col = 4 * cg + 1 + k;
                unsigned int pk = (unsigned int)f2bf(a[k]) | ((unsigned int)f2bf(c[k]) << 16);
                const int e = ((row * XC + col) * CIN + ci) ^ ((col & 7) * 8);
                *(unsigned int*)&xs[e] = pk;
            }
        }
        // halo cols: col 0 (gw = w0-1) and col 33 (gw = w0+32)
        for (int i = tid; i < 2 * XR * CIN; i += 512) {
            const int side = (i >= XR * CIN) ? 1 : 0;
            const int rem  = i - side * XR * CIN;
            const int row  = rem >> 6;
            const int ci   = rem & 63;
            const int col  = side ? (XC - 1) : 0;
            const int gh   = h0 - 1 + row;
            const int gw   = side ? (w0 + TW) : (w0 - 1);
            float v = 0.f;
            if ((unsigned)gh < HH && (unsigned)gw < WW)
                v = xb[((size_t)ci * HH + gh) * WW + gw];
            const int e = ((row * XC + col) * CIN + ci) ^ ((col & 7) * 8);
            xs[e] = f2bf(v);
        }
    }

    __syncthreads();   // full drain: tap-0 weights + x tile ready

    // ---------- compute: wave tiling ----------
    const int wm   = wid & 1;        // co block of 64
    const int wn   = wid >> 1;       // 2 h-rows of 32 cols each
    const int c15  = lane & 15;
    const int q8   = (lane >> 4) * 8;
    const int par  = lane & 1;       // parity of output column (w0 even)

    const int aBase = (wm * 64 + c15) * CIN + q8;
    const int swzA  = (c15 & 7) * 8;

    f32x4 acc[4][4];
    #pragma unroll
    for (int mi = 0; mi < 4; ++mi)
        #pragma unroll
        for (int ni = 0; ni < 4; ++ni)
            acc[mi][ni] = (f32x4)0.0f;

    #pragma unroll
    for (int tap = 0; tap < 7; ++tap) {
        // issue next tap's weight loads; they stay in flight under this tap's MFMAs
        if (tap < 6) {
            stage_tap(tap + 1, (tap + 1) & 1);
            asm volatile("s_waitcnt vmcnt(2)" ::: "memory");   // tap t's loads landed
        } else {
            asm volatile("s_waitcnt vmcnt(0)" ::: "memory");
        }
        __builtin_amdgcn_s_barrier();          // all waves' tap-t weights visible
        __builtin_amdgcn_sched_barrier(0);

        const unsigned short* wc = wtb + (tap & 1) * WTAP;

        // B-operand address parameters for this tap
        int R0, P, C0;
        if (tap < 3) { R0 = tap; P = 0; C0 = 1; }                   // vertical 3x1
        else { R0 = (tap - 3) >> 1; P = 1; C0 = ((tap - 3) & 1) * 2; } // hex 2x2
        const int colb  = c15 + C0;                 // + chalf*16 later (&7 invariant)
        const int swzB  = (colb & 7) * 8;
        const int bBase = ((wn * 2 + R0 + P * par) * XC + colb) * CIN + q8;

        #pragma unroll
        for (int ci0 = 0; ci0 < CIN; ci0 += 32) {
            short8 af[4];
            #pragma unroll
            for (int mi = 0; mi < 4; ++mi)
                af[mi] = *(const short8*)&wc[(aBase + mi * 16 * CIN + ci0) ^ swzA];
            #pragma unroll
            for (int ni = 0; ni < 4; ++ni) {
                const int hr = ni >> 1, chalf = ni & 1;
                const int e = (bBase + hr * (XC * CIN) + chalf * (16 * CIN) + ci0) ^ swzB;
                short8 bf = *(const short8*)&xs[e];
                #pragma unroll
                for (int mi = 0; mi < 4; ++mi)
                    acc[mi][ni] = __builtin_amdgcn_mfma_f32_16x16x32_bf16(
                        af[mi], bf, acc[mi][ni], 0, 0, 0);
            }
        }

        // all our ds_reads done -> safe for others to overwrite buffers next iter
        asm volatile("s_waitcnt lgkmcnt(0)" ::: "memory");
        __builtin_amdgcn_sched_barrier(0);
        __builtin_amdgcn_s_barrier();
    }

    // ---------- epilogue: LDS bounce for fully-coalesced 128B row stores ----------
    // C/D layout (16x16): col = lane&15, row = (lane>>4)*4 + reg
    #pragma unroll
    for (int p = 0; p < 2; ++p) {
        if (wm == p) {
            #pragma unroll
            for (int mi = 0; mi < 4; ++mi) {
                #pragma unroll
                for (int ni = 0; ni < 4; ++ni) {
                    const int hh   = wn * 2 + (ni >> 1);
                    const int wloc = (ni & 1) * 16 + c15;
                    #pragma unroll
                    for (int r = 0; r < 4; ++r) {
                        const int col = mi * 16 + (lane >> 4) * 4 + r;   // local co 0..63
                        ot[(col * TH + hh) * OT_STRIDE + wloc] =
                            acc[mi][ni][r] + bias_lds[p * 64 + col];
                    }
                }
            }
        }
        asm volatile("s_waitcnt lgkmcnt(0)" ::: "memory");
        __builtin_amdgcn_sched_barrier(0);
        __builtin_amdgcn_s_barrier();
        // 512 threads x 8 iters = 4096 float4 = 64co x 8h x 32w
        #pragma unroll
        for (int it = 0; it < 8; ++it) {
            const int col = it * 8 + (tid >> 6);     // local co
            const int hh  = (tid >> 3) & 7;
            const int w4  = (tid & 7) * 4;
            const float* src = &ot[(col * TH + hh) * OT_STRIDE + w4];
            f32x4 v = { src[0], src[1], src[2], src[3] };
            __builtin_nontemporal_store(v,
                (f32x4*)&out[(((size_t)b * COUT + p * 64 + col) * HH + h0 + hh) * WW + w0 + w4]);
        }
        if (p == 0) {
            asm volatile("s_waitcnt lgkmcnt(0)" ::: "memory");
            __builtin_amdgcn_sched_barrier(0);
            __builtin_amdgcn_s_barrier();     // ot reads done before p=1 overwrites
        }
    }
}

extern "C" void kernel_launch(void* const* d_in, const int* in_sizes, int n_in,
                              void* d_out, int out_size, void* d_ws, size_t ws_size,
                              hipStream_t stream) {
    const float* x    = (const float*)d_in[0];
    const float* k0   = (const float*)d_in[1];
    const float* k1   = (const float*)d_in[2];
    const float* bias = (const float*)d_in[3];
    float* out        = (float*)d_out;
    unsigned short* wsw = (unsigned short*)d_ws;   // 7*128*64*2 = 114688 B

    prep_weights<<<dim3(14, 1, 1), 512, 0, stream>>>(k0, k1, wsw);
    hexconv_mfma<<<dim3(2048, 1, 1), 512, 0, stream>>>(x, wsw, bias, out);
}